// Round 9
// baseline (262.465 us; speedup 1.0000x reference)
//
#include <hip/hip_runtime.h>

#define N_NODES 40000
#define N_EDGES 640000
#define IN_F 128
#define HID_F 256
#define CLS_F 40
#define CLS_P 48      // padded to 3 MFMA tiles of 16
#define MB 32         // nodes per block in fused MLP (2 row-tiles of 16; 1250 blocks)
#define TS_LD 264     // ushort row stride for relu intermediate (>=256, 16B-aligned, 2-way banks)
#define A_LD 136      // ushort row stride for gathered A tile (272B, 16B-aligned)

typedef __attribute__((ext_vector_type(8))) short bf16x8;
typedef __attribute__((ext_vector_type(4))) float f32x4;
typedef __attribute__((ext_vector_type(4))) _Float16 half4;
typedef __attribute__((ext_vector_type(8))) _Float16 half8;

#define MFMA(a, b, c) __builtin_amdgcn_mfma_f32_16x16x32_bf16(a, b, c, 0, 0, 0)

__device__ __forceinline__ unsigned short f32_to_bf16_rne(float f) {
    unsigned int u = __float_as_uint(f);
    unsigned int r = u + 0x7fffu + ((u >> 16) & 1u);
    return (unsigned short)(r >> 16);
}

// XOR swizzle for the A tile: permute 16B blocks within a row by row&7 so that
// A-fragment ds_read_b128 (16 rows at fixed col-block) spreads across 8 bank
// groups (2-way residual = free). Applied on BOTH write and read.
__device__ __forceinline__ int aswz(int row, int col_us) {
    return row * A_LD + (col_us ^ ((row & 7) << 3));
}

// ---------------- CSR build ----------------

__global__ void k_count(const int* __restrict__ dst, int* __restrict__ counts) {
    int e = blockIdx.x * blockDim.x + threadIdx.x;
    if (e < N_EDGES) atomicAdd(&counts[dst[e]], 1);
}

__global__ void k_scan1(const int* __restrict__ counts, int* __restrict__ bsum) {
    __shared__ int s[256];
    int i = blockIdx.x * 256 + threadIdx.x;
    s[threadIdx.x] = (i < N_NODES) ? counts[i] : 0;
    __syncthreads();
    for (int off = 128; off > 0; off >>= 1) {
        if (threadIdx.x < off) s[threadIdx.x] += s[threadIdx.x + off];
        __syncthreads();
    }
    if (threadIdx.x == 0) bsum[blockIdx.x] = s[0];
}

// parallel exclusive scan over <=256 block sums (157 used)
__global__ void k_scan2(int* __restrict__ bsum, int nb) {
    __shared__ int s[256];
    int t = threadIdx.x;
    int v = (t < nb) ? bsum[t] : 0;
    s[t] = v;
    __syncthreads();
    for (int off = 1; off < 256; off <<= 1) {
        int x = (t >= off) ? s[t - off] : 0;
        __syncthreads();
        s[t] += x;
        __syncthreads();
    }
    if (t < nb) bsum[t] = s[t] - v;   // exclusive
}

// scan3 + norm fused (norm needs only counts, which are already in hand)
__global__ void k_scan3n(const int* __restrict__ counts, const int* __restrict__ bsum,
                         int* __restrict__ rowptr, int* __restrict__ cursor,
                         float* __restrict__ norm, float* __restrict__ norm2) {
    __shared__ int s[256];
    int t = threadIdx.x;
    int i = blockIdx.x * 256 + t;
    int v = (i < N_NODES) ? counts[i] : 0;
    s[t] = v;
    __syncthreads();
    for (int off = 1; off < 256; off <<= 1) {
        int x = (t >= off) ? s[t - off] : 0;
        __syncthreads();
        s[t] += x;
        __syncthreads();
    }
    if (i < N_NODES) {
        int excl = s[t] - v + bsum[blockIdx.x];
        rowptr[i] = excl;
        cursor[i] = excl;
        float d = (float)v;
        float r = rsqrtf(fmaxf(d, 1.0f));
        norm[i] = r;
        norm2[i] = r * r;
    }
}

// ---------------- fill + scale + prep fused (all depend only on scan3n) ----------------
// blocks [0,2500): csr fill; [2500,5000): xs = fp16(features*norm); [5000,5176): weight prep

__global__ __launch_bounds__(256) void k_fsp(
        const int* __restrict__ src, const int* __restrict__ dst,
        int* __restrict__ cursor, unsigned short* __restrict__ csr_src,
        const float* __restrict__ features, const float* __restrict__ norm,
        _Float16* __restrict__ xs,
        const float* __restrict__ W1, const float* __restrict__ W2,
        unsigned short* __restrict__ w1hi, unsigned short* __restrict__ w1lo,
        unsigned short* __restrict__ w2hi, unsigned short* __restrict__ w2lo) {
    int b = blockIdx.x;
    if (b < 2500) {
        int e = b * 256 + threadIdx.x;            // exactly N_EDGES threads
        int d = dst[e];
        int p = atomicAdd(&cursor[d], 1);
        csr_src[p] = (unsigned short)src[e];      // N_NODES < 65536
    } else if (b < 5000) {
        int i = (b - 2500) * 256 + threadIdx.x;   // 8 floats per thread, 640000 total
        float s = norm[i >> 4];                   // 16 threads per 128-elem row
        float4 a = ((const float4*)features)[i * 2];
        float4 c = ((const float4*)features)[i * 2 + 1];
        half8 h;
        h[0] = (_Float16)(a.x * s); h[1] = (_Float16)(a.y * s);
        h[2] = (_Float16)(a.z * s); h[3] = (_Float16)(a.w * s);
        h[4] = (_Float16)(c.x * s); h[5] = (_Float16)(c.y * s);
        h[6] = (_Float16)(c.z * s); h[7] = (_Float16)(c.w * s);
        ((half8*)xs)[i] = h;
    } else {
        int idx = (b - 5000) * 256 + threadIdx.x;
        if (idx < IN_F * HID_F) {
            int k = idx >> 8;
            int c = idx & 255;
            float v = W1[idx];
            unsigned short hi = f32_to_bf16_rne(v);
            float fh = __uint_as_float((unsigned)hi << 16);
            w1hi[c * IN_F + k] = hi;
            w1lo[c * IN_F + k] = f32_to_bf16_rne(v - fh);
        }
        int idx2 = idx - IN_F * HID_F;
        if (idx2 >= 0 && idx2 < CLS_P * HID_F) {
            int c = idx2 >> 8;
            int k = idx2 & 255;
            float v = (c < CLS_F) ? W2[k * CLS_F + c] : 0.f;
            unsigned short hi = f32_to_bf16_rne(v);
            float fh = __uint_as_float((unsigned)hi << 16);
            w2hi[c * HID_F + k] = hi;
            w2lo[c * HID_F + k] = f32_to_bf16_rne(v - fh);
        }
    }
}

// ---------------- hop1 (gather, fp16 tables) ----------------
// 32 lanes per node, half4 (8B) per lane -> one 256B row read per edge.
// h1[n] = fp16( norm2[n] * sum_{s in in(n)} xs[s] )

__global__ __launch_bounds__(256) void k_hop(
        const _Float16* __restrict__ gin, _Float16* __restrict__ gout,
        const unsigned short* __restrict__ csr_src, const int* __restrict__ rowptr,
        const int* __restrict__ counts, const float* __restrict__ oscale) {
    int gid  = blockIdx.x * 8 + (threadIdx.x >> 5);
    int lane = threadIdx.x & 31;
    if (gid >= N_NODES) return;
    int start = rowptr[gid];
    int cnt   = counts[gid];
    const _Float16* base = gin + lane * 4;
    float4 acc = make_float4(0.f, 0.f, 0.f, 0.f);
    int i = 0;
    for (; i + 3 < cnt; i += 4) {
        int s0 = csr_src[start + i];     int s1 = csr_src[start + i + 1];
        int s2 = csr_src[start + i + 2]; int s3 = csr_src[start + i + 3];
        half4 v0 = *(const half4*)(base + (size_t)s0 * IN_F);
        half4 v1 = *(const half4*)(base + (size_t)s1 * IN_F);
        half4 v2 = *(const half4*)(base + (size_t)s2 * IN_F);
        half4 v3 = *(const half4*)(base + (size_t)s3 * IN_F);
        acc.x += (float)v0[0] + (float)v1[0] + (float)v2[0] + (float)v3[0];
        acc.y += (float)v0[1] + (float)v1[1] + (float)v2[1] + (float)v3[1];
        acc.z += (float)v0[2] + (float)v1[2] + (float)v2[2] + (float)v3[2];
        acc.w += (float)v0[3] + (float)v1[3] + (float)v2[3] + (float)v3[3];
    }
    for (; i < cnt; i++) {
        int s = csr_src[start + i];
        half4 v = *(const half4*)(base + (size_t)s * IN_F);
        acc.x += (float)v[0]; acc.y += (float)v[1];
        acc.z += (float)v[2]; acc.w += (float)v[3];
    }
    float sc = oscale[gid];
    half4 o;
    o[0] = (_Float16)(acc.x * sc); o[1] = (_Float16)(acc.y * sc);
    o[2] = (_Float16)(acc.z * sc); o[3] = (_Float16)(acc.w * sc);
    *(half4*)(gout + (size_t)gid * IN_F + lane * 4) = o;
}

// ---------------- fused hop2 + MLP ----------------
// Phase 1 (gather): 8 groups of 32 lanes gather the block's 32 node rows from
// h1 (fp16), scale by norm[n] (trailing SGConv norm), split bf16 hi/lo into a
// swizzled LDS A-tile.  Phase 2: GEMM1 with W1 fragments preloaded in VGPRs
// (A-frags now ds_read_b128 from LDS).  Phase 3: GEMM2, W2 frags in VGPRs.
// Blocks in phase 1 (fabric-bound) overlap blocks in phases 2-3 (MFMA-bound)
// on the same CU.

__global__ __launch_bounds__(256, 2) void k_mlp(
        const _Float16* __restrict__ h1,
        const unsigned short* __restrict__ csr_src, const int* __restrict__ rowptr,
        const int* __restrict__ counts, const float* __restrict__ norm,
        const unsigned short* __restrict__ w1hi, const unsigned short* __restrict__ w1lo,
        const float* __restrict__ b1,
        const unsigned short* __restrict__ w2hi, const unsigned short* __restrict__ w2lo,
        const float* __restrict__ b2,
        float* __restrict__ out) {
    __shared__ __align__(16) unsigned short ahi[MB * A_LD];    // 8.5 KB
    __shared__ __align__(16) unsigned short alo[MB * A_LD];    // 8.5 KB
    __shared__ __align__(16) unsigned short tshi[MB * TS_LD];  // 16.5 KB
    __shared__ __align__(16) unsigned short tslo[MB * TS_LD];  // 16.5 KB
    int n0 = blockIdx.x * MB;
    int t  = threadIdx.x;
    int w  = t >> 6;
    int l  = t & 63;
    int lr = l & 15;     // A-row / B-col within tile
    int lg = l >> 4;     // k-group

    // ---- preload W1 fragments (latency hides under the gather phase) ----
    bf16x8 b1h[4][4], b1l[4][4];
    float  b1v[4];
    #pragma unroll
    for (int ct = 0; ct < 4; ct++) {
        int col = w * 64 + ct * 16 + lr;
        const unsigned short* bhp = w1hi + (size_t)col * IN_F + lg * 8;
        const unsigned short* blp = w1lo + (size_t)col * IN_F + lg * 8;
        #pragma unroll
        for (int kq = 0; kq < 4; kq++) {
            b1h[ct][kq] = *(const bf16x8*)(bhp + kq * 32);
            b1l[ct][kq] = *(const bf16x8*)(blp + kq * 32);
        }
        b1v[ct] = b1[col];
    }

    // ---- phase 1: gather 32 rows of h1 into swizzled bf16 hi/lo A-tile ----
    {
        int grp  = t >> 5;          // 0..7
        int lane = t & 31;
        for (int nn = grp; nn < MB; nn += 8) {
            int gid = n0 + nn;
            int start = rowptr[gid];
            int cnt   = counts[gid];
            const _Float16* base = h1 + lane * 4;
            float4 acc = make_float4(0.f, 0.f, 0.f, 0.f);
            int i = 0;
            for (; i + 3 < cnt; i += 4) {
                int s0 = csr_src[start + i];     int s1 = csr_src[start + i + 1];
                int s2 = csr_src[start + i + 2]; int s3 = csr_src[start + i + 3];
                half4 v0 = *(const half4*)(base + (size_t)s0 * IN_F);
                half4 v1 = *(const half4*)(base + (size_t)s1 * IN_F);
                half4 v2 = *(const half4*)(base + (size_t)s2 * IN_F);
                half4 v3 = *(const half4*)(base + (size_t)s3 * IN_F);
                acc.x += (float)v0[0] + (float)v1[0] + (float)v2[0] + (float)v3[0];
                acc.y += (float)v0[1] + (float)v1[1] + (float)v2[1] + (float)v3[1];
                acc.z += (float)v0[2] + (float)v1[2] + (float)v2[2] + (float)v3[2];
                acc.w += (float)v0[3] + (float)v1[3] + (float)v2[3] + (float)v3[3];
            }
            for (; i < cnt; i++) {
                int s = csr_src[start + i];
                half4 v = *(const half4*)(base + (size_t)s * IN_F);
                acc.x += (float)v[0]; acc.y += (float)v[1];
                acc.z += (float)v[2]; acc.w += (float)v[3];
            }
            float sc = norm[gid];
            float vv[4] = {acc.x * sc, acc.y * sc, acc.z * sc, acc.w * sc};
            ushort4 h, lo4;
            unsigned short* hp = (unsigned short*)&h;
            unsigned short* lp = (unsigned short*)&lo4;
            #pragma unroll
            for (int j = 0; j < 4; j++) {
                unsigned short hi = f32_to_bf16_rne(vv[j]);
                float fh = __uint_as_float((unsigned)hi << 16);
                hp[j] = hi;
                lp[j] = f32_to_bf16_rne(vv[j] - fh);
            }
            int o = aswz(nn, lane * 4);   // ushort4 stays within one 16B block
            *(ushort4*)&ahi[o] = h;
            *(ushort4*)&alo[o] = lo4;
        }
    }
    __syncthreads();

    // ---- phase 2: GEMM1, A-frags from swizzled LDS ----
    #pragma unroll
    for (int rt = 0; rt < 2; rt++) {
        bf16x8 aH[4], aL[4];
        #pragma unroll
        for (int kq = 0; kq < 4; kq++) {
            int o = aswz(rt * 16 + lr, (kq * 4 + lg) * 8);
            aH[kq] = *(const bf16x8*)&ahi[o];
            aL[kq] = *(const bf16x8*)&alo[o];
        }
        #pragma unroll
        for (int ct = 0; ct < 4; ct++) {
            f32x4 acc = {0.f, 0.f, 0.f, 0.f};
            #pragma unroll
            for (int kq = 0; kq < 4; kq++) {
                acc = MFMA(aH[kq], b1h[ct][kq], acc);
                acc = MFMA(aH[kq], b1l[ct][kq], acc);
                acc = MFMA(aL[kq], b1h[ct][kq], acc);
            }
            int col = w * 64 + ct * 16 + lr;
            #pragma unroll
            for (int r = 0; r < 4; r++) {
                int row = rt * 16 + lg * 4 + r;     // C layout: row=(lane>>4)*4+reg
                float v = acc[r] + b1v[ct];
                v = v > 0.f ? v : 0.f;
                unsigned short hi = f32_to_bf16_rne(v);
                float fh = __uint_as_float((unsigned)hi << 16);
                tshi[row * TS_LD + col] = hi;
                tslo[row * TS_LD + col] = f32_to_bf16_rne(v - fh);
            }
        }
    }
    __syncthreads();

    // ---- phase 3: GEMM2, waves 0-2, one 16-class col-tile each ----
    if (w < 3) {
        int col = w * 16 + lr;                     // 0..47 (padded)
        bf16x8 b2h[8], b2l[8];
        const unsigned short* bhp = w2hi + (size_t)col * HID_F + lg * 8;
        const unsigned short* blp = w2lo + (size_t)col * HID_F + lg * 8;
        #pragma unroll
        for (int kk = 0; kk < 8; kk++) {
            b2h[kk] = *(const bf16x8*)(bhp + kk * 32);
            b2l[kk] = *(const bf16x8*)(blp + kk * 32);
        }
        float bias = (col < CLS_F) ? b2[col] : 0.f;
        #pragma unroll
        for (int rt2 = 0; rt2 < 2; rt2++) {
            const unsigned short* ahp = tshi + (rt2 * 16 + lr) * TS_LD + lg * 8;
            const unsigned short* alp = tslo + (rt2 * 16 + lr) * TS_LD + lg * 8;
            f32x4 acc0 = {0.f, 0.f, 0.f, 0.f};
            f32x4 acc1 = {0.f, 0.f, 0.f, 0.f};
            #pragma unroll
            for (int kk = 0; kk < 4; kk++) {
                bf16x8 a_h0 = *(const bf16x8*)(ahp + kk * 32);
                bf16x8 a_l0 = *(const bf16x8*)(alp + kk * 32);
                bf16x8 a_h1 = *(const bf16x8*)(ahp + (kk + 4) * 32);
                bf16x8 a_l1 = *(const bf16x8*)(alp + (kk + 4) * 32);
                acc0 = MFMA(a_h0, b2h[kk], acc0);
                acc1 = MFMA(a_h1, b2h[kk + 4], acc1);
                acc0 = MFMA(a_h0, b2l[kk], acc0);
                acc1 = MFMA(a_h1, b2l[kk + 4], acc1);
                acc0 = MFMA(a_l0, b2h[kk], acc0);
                acc1 = MFMA(a_l1, b2h[kk + 4], acc1);
            }
            if (col < CLS_F) {
                #pragma unroll
                for (int r = 0; r < 4; r++) {
                    int mrow = n0 + rt2 * 16 + lg * 4 + r;
                    out[(size_t)mrow * CLS_F + col] = acc0[r] + acc1[r] + bias;
                }
            }
        }
    }
}

// ---------------- launch ----------------

extern "C" void kernel_launch(void* const* d_in, const int* in_sizes, int n_in,
                              void* d_out, int out_size, void* d_ws, size_t ws_size,
                              hipStream_t stream) {
    const float* features = (const float*)d_in[0];
    const int*   src      = (const int*)d_in[1];
    const int*   dst      = (const int*)d_in[2];
    const float* W1       = (const float*)d_in[3];
    const float* b1       = (const float*)d_in[4];
    const float* W2       = (const float*)d_in[5];
    const float* b2       = (const float*)d_in[6];
    float*       out      = (float*)d_out;

    char* ws = (char*)d_ws;
    size_t off = 0;
    auto alloc = [&](size_t bytes) -> void* {
        void* p = ws + off;
        off += (bytes + 255) & ~(size_t)255;
        return p;
    };
    int*   counts = (int*)alloc((size_t)N_NODES * 4);
    int*   rowptr = (int*)alloc((size_t)N_NODES * 4);
    int*   cursor = (int*)alloc((size_t)N_NODES * 4);
    int*   bsum   = (int*)alloc(256 * 4);
    float* norm   = (float*)alloc((size_t)N_NODES * 4);
    float* norm2  = (float*)alloc((size_t)N_NODES * 4);
    unsigned short* csr = (unsigned short*)alloc((size_t)N_EDGES * 2);
    _Float16* xs  = (_Float16*)alloc((size_t)N_NODES * IN_F * 2);
    _Float16* h1  = (_Float16*)alloc((size_t)N_NODES * IN_F * 2);
    unsigned short* w1hi = (unsigned short*)alloc((size_t)HID_F * IN_F * 2);
    unsigned short* w1lo = (unsigned short*)alloc((size_t)HID_F * IN_F * 2);
    unsigned short* w2hi = (unsigned short*)alloc((size_t)CLS_P * HID_F * 2);
    unsigned short* w2lo = (unsigned short*)alloc((size_t)CLS_P * HID_F * 2);

    hipMemsetAsync(counts, 0, (size_t)N_NODES * 4, stream);

    int nb = (N_NODES + 255) / 256;   // 157
    k_count<<<(N_EDGES + 255) / 256, 256, 0, stream>>>(dst, counts);
    k_scan1<<<nb, 256, 0, stream>>>(counts, bsum);
    k_scan2<<<1, 256, 0, stream>>>(bsum, nb);
    k_scan3n<<<nb, 256, 0, stream>>>(counts, bsum, rowptr, cursor, norm, norm2);

    int prep_blocks = (IN_F * HID_F + CLS_P * HID_F + 255) / 256;   // 176
    k_fsp<<<5000 + prep_blocks, 256, 0, stream>>>(
        src, dst, cursor, csr, features, norm, xs, W1, W2, w1hi, w1lo, w2hi, w2lo);

    // hop1: h1 = fp16(norm2 * (A @ xs));  hop2+MLP fused
    k_hop<<<(N_NODES + 7) / 8, 256, 0, stream>>>(xs, h1, csr, rowptr, counts, norm2);
    k_mlp<<<N_NODES / MB, 256, 0, stream>>>(h1, csr, rowptr, counts, norm,
                                            w1hi, w1lo, b1, w2hi, w2lo, b2, out);
}

// Round 10
// 227.754 us; speedup vs baseline: 1.1524x; 1.1524x over previous
//
#include <hip/hip_runtime.h>

#define N_NODES 40000
#define N_EDGES 640000
#define IN_F 128
#define HID_F 256
#define CLS_F 40
#define CLS_P 48      // padded to 3 MFMA tiles of 16
#define MB 32         // nodes per block in fused MLP (2 row-tiles of 16; 1250 blocks)
#define TS_LD 264     // ushort row stride: MUST be >= 256 (row width); 528B, 16B-aligned

typedef __attribute__((ext_vector_type(8))) short bf16x8;
typedef __attribute__((ext_vector_type(4))) float f32x4;
typedef __attribute__((ext_vector_type(4))) _Float16 half4;
typedef __attribute__((ext_vector_type(8))) _Float16 half8;

#define MFMA(a, b, c) __builtin_amdgcn_mfma_f32_16x16x32_bf16(a, b, c, 0, 0, 0)

__device__ __forceinline__ unsigned short f32_to_bf16_rne(float f) {
    unsigned int u = __float_as_uint(f);
    unsigned int r = u + 0x7fffu + ((u >> 16) & 1u);
    return (unsigned short)(r >> 16);
}

// ---------------- CSR build ----------------

__global__ void k_count(const int* __restrict__ dst, int* __restrict__ counts,
                        int* __restrict__ gcur) {
    int e = blockIdx.x * blockDim.x + threadIdx.x;
    if (e == 0) *gcur = 0;              // consumed only by k_scanA (next launch)
    if (e < N_EDGES) atomicAdd(&counts[dst[e]], 1);
}

// single-kernel scan: local 256-scan + one atomicAdd to claim a disjoint range.
// rowptr ranges need NOT be monotonic across blocks -- any disjoint layout is a
// valid CSR (fill scatters via cursor, gathers read rowptr[gid] only).
__global__ void k_scanA(const int* __restrict__ counts, int* __restrict__ gcur,
                        int* __restrict__ rowptr, int* __restrict__ cursor,
                        float* __restrict__ norm, float* __restrict__ norm2) {
    __shared__ int s[256];
    __shared__ int base;
    int t = threadIdx.x;
    int i = blockIdx.x * 256 + t;
    int v = (i < N_NODES) ? counts[i] : 0;
    s[t] = v;
    __syncthreads();
    for (int off = 1; off < 256; off <<= 1) {
        int x = (t >= off) ? s[t - off] : 0;
        __syncthreads();
        s[t] += x;
        __syncthreads();
    }
    if (t == 255) base = atomicAdd(gcur, s[255]);
    __syncthreads();
    if (i < N_NODES) {
        int excl = base + s[t] - v;
        rowptr[i] = excl;
        cursor[i] = excl;
        float r = rsqrtf(fmaxf((float)v, 1.0f));
        norm[i] = r;
        norm2[i] = r * r;
    }
}

// ---------------- fill + scale + prep fused (all depend only on scanA) ----------------
// blocks [0,2500): csr fill; [2500,5000): xs = fp16(features*norm); [5000,5176): weight prep

__global__ __launch_bounds__(256) void k_fsp(
        const int* __restrict__ src, const int* __restrict__ dst,
        int* __restrict__ cursor, unsigned short* __restrict__ csr_src,
        const float* __restrict__ features, const float* __restrict__ norm,
        _Float16* __restrict__ xs,
        const float* __restrict__ W1, const float* __restrict__ W2,
        unsigned short* __restrict__ w1hi, unsigned short* __restrict__ w1lo,
        unsigned short* __restrict__ w2hi, unsigned short* __restrict__ w2lo) {
    int b = blockIdx.x;
    if (b < 2500) {
        int e = b * 256 + threadIdx.x;            // exactly N_EDGES threads
        int d = dst[e];
        int p = atomicAdd(&cursor[d], 1);
        csr_src[p] = (unsigned short)src[e];      // N_NODES < 65536
    } else if (b < 5000) {
        int i = (b - 2500) * 256 + threadIdx.x;   // 8 floats per thread, 640000 total
        float s = norm[i >> 4];                   // 16 threads per 128-elem row
        float4 a = ((const float4*)features)[i * 2];
        float4 c = ((const float4*)features)[i * 2 + 1];
        half8 h;
        h[0] = (_Float16)(a.x * s); h[1] = (_Float16)(a.y * s);
        h[2] = (_Float16)(a.z * s); h[3] = (_Float16)(a.w * s);
        h[4] = (_Float16)(c.x * s); h[5] = (_Float16)(c.y * s);
        h[6] = (_Float16)(c.z * s); h[7] = (_Float16)(c.w * s);
        ((half8*)xs)[i] = h;
    } else {
        int idx = (b - 5000) * 256 + threadIdx.x;
        if (idx < IN_F * HID_F) {
            int k = idx >> 8;
            int c = idx & 255;
            float v = W1[idx];
            unsigned short hi = f32_to_bf16_rne(v);
            float fh = __uint_as_float((unsigned)hi << 16);
            w1hi[c * IN_F + k] = hi;
            w1lo[c * IN_F + k] = f32_to_bf16_rne(v - fh);
        }
        int idx2 = idx - IN_F * HID_F;
        if (idx2 >= 0 && idx2 < CLS_P * HID_F) {
            int c = idx2 >> 8;
            int k = idx2 & 255;
            float v = (c < CLS_F) ? W2[k * CLS_F + c] : 0.f;
            unsigned short hi = f32_to_bf16_rne(v);
            float fh = __uint_as_float((unsigned)hi << 16);
            w2hi[c * HID_F + k] = hi;
            w2lo[c * HID_F + k] = f32_to_bf16_rne(v - fh);
        }
    }
}

// ---------------- propagation hops (gather, fp16 tables) ----------------
// 32 lanes per node, half4 (8B) per lane -> one 256B row read per edge.
// Pure gather-sum in fp32; dst-side scaling in epilogue.

#define HOP_GATHER16                                                          \
    int gid  = blockIdx.x * 8 + (threadIdx.x >> 5);                           \
    int lane = threadIdx.x & 31;                                              \
    if (gid >= N_NODES) return;                                               \
    int start = rowptr[gid];                                                  \
    int cnt   = counts[gid];                                                  \
    const _Float16* base = gin + lane * 4;                                    \
    float4 acc = make_float4(0.f, 0.f, 0.f, 0.f);                             \
    int i = 0;                                                                \
    for (; i + 3 < cnt; i += 4) {                                             \
        int s0 = csr_src[start + i];     int s1 = csr_src[start + i + 1];     \
        int s2 = csr_src[start + i + 2]; int s3 = csr_src[start + i + 3];     \
        half4 v0 = *(const half4*)(base + (size_t)s0 * IN_F);                 \
        half4 v1 = *(const half4*)(base + (size_t)s1 * IN_F);                 \
        half4 v2 = *(const half4*)(base + (size_t)s2 * IN_F);                 \
        half4 v3 = *(const half4*)(base + (size_t)s3 * IN_F);                 \
        acc.x += (float)v0[0] + (float)v1[0] + (float)v2[0] + (float)v3[0];   \
        acc.y += (float)v0[1] + (float)v1[1] + (float)v2[1] + (float)v3[1];   \
        acc.z += (float)v0[2] + (float)v1[2] + (float)v2[2] + (float)v3[2];   \
        acc.w += (float)v0[3] + (float)v1[3] + (float)v2[3] + (float)v3[3];   \
    }                                                                         \
    for (; i < cnt; i++) {                                                    \
        int s = csr_src[start + i];                                           \
        half4 v = *(const half4*)(base + (size_t)s * IN_F);                   \
        acc.x += (float)v[0]; acc.y += (float)v[1];                           \
        acc.z += (float)v[2]; acc.w += (float)v[3];                           \
    }

// hop1: gout[n] = fp16( oscale[n] * sum )   (oscale = norm^2)
__global__ __launch_bounds__(256) void k_hop(
        const _Float16* __restrict__ gin, _Float16* __restrict__ gout,
        const unsigned short* __restrict__ csr_src, const int* __restrict__ rowptr,
        const int* __restrict__ counts, const float* __restrict__ oscale) {
    HOP_GATHER16
    float sc = oscale[gid];
    half4 o;
    o[0] = (_Float16)(acc.x * sc); o[1] = (_Float16)(acc.y * sc);
    o[2] = (_Float16)(acc.z * sc); o[3] = (_Float16)(acc.w * sc);
    *(half4*)(gout + (size_t)gid * IN_F + lane * 4) = o;
}

// hop2: bf16 hi/lo split output (feeds MFMA MLP), oscale = norm (trailing norm)
__global__ __launch_bounds__(256) void k_hop_split(
        const _Float16* __restrict__ gin,
        unsigned short* __restrict__ ghi, unsigned short* __restrict__ glo,
        const unsigned short* __restrict__ csr_src, const int* __restrict__ rowptr,
        const int* __restrict__ counts, const float* __restrict__ oscale) {
    HOP_GATHER16
    float sc = oscale[gid];
    float vv[4] = {acc.x * sc, acc.y * sc, acc.z * sc, acc.w * sc};
    ushort4 h, l;
    unsigned short* hp = (unsigned short*)&h;
    unsigned short* lp = (unsigned short*)&l;
    #pragma unroll
    for (int j = 0; j < 4; j++) {
        unsigned short hi = f32_to_bf16_rne(vv[j]);
        float fh = __uint_as_float((unsigned)hi << 16);
        hp[j] = hi;
        lp[j] = f32_to_bf16_rne(vv[j] - fh);
    }
    ((ushort4*)(ghi + (size_t)gid * IN_F))[lane] = h;
    ((ushort4*)(glo + (size_t)gid * IN_F))[lane] = l;
}

// ---------------- fused MLP via split-bf16 MFMA, weights-in-registers ----------------
// D = Ahi*Bhi + Ahi*Blo + Alo*Bhi (fp32 accum).
// Block: 4 waves, MB=32 rows (2 row-tiles of 16). Wave w owns GEMM1 cols
// [w*64, w*64+64): its 32 W1 fragments (128 VGPR) are preloaded ONCE, then the
// 2 row-tiles stream through with A double-buffered. GEMM2: waves 0-2 each own
// one 16-class col-tile with 16 W2 fragments (64 VGPR) preloaded.

#define LOAD_A(AH, AL, rt) do {                                              \
    const unsigned short* hp_ = h2hi + (size_t)(n0 + (rt) * 16 + lr) * IN_F + lg * 8; \
    const unsigned short* lp_ = h2lo + (size_t)(n0 + (rt) * 16 + lr) * IN_F + lg * 8; \
    _Pragma("unroll")                                                        \
    for (int kq = 0; kq < 4; kq++) {                                         \
        AH[kq] = *(const bf16x8*)(hp_ + kq * 32);                            \
        AL[kq] = *(const bf16x8*)(lp_ + kq * 32);                            \
    }                                                                        \
} while (0)

#define TILE(AH, AL, rt) do {                                                \
    _Pragma("unroll")                                                        \
    for (int ct = 0; ct < 4; ct++) {                                         \
        f32x4 acc = {0.f, 0.f, 0.f, 0.f};                                    \
        _Pragma("unroll")                                                    \
        for (int kq = 0; kq < 4; kq++) {                                     \
            acc = MFMA(AH[kq], b1h[ct][kq], acc);                            \
            acc = MFMA(AH[kq], b1l[ct][kq], acc);                            \
            acc = MFMA(AL[kq], b1h[ct][kq], acc);                            \
        }                                                                    \
        int col_ = w * 64 + ct * 16 + lr;                                    \
        _Pragma("unroll")                                                    \
        for (int r = 0; r < 4; r++) {                                        \
            int row_ = (rt) * 16 + lg * 4 + r;                               \
            float v_ = acc[r] + b1v[ct];                                     \
            v_ = v_ > 0.f ? v_ : 0.f;                                        \
            unsigned short hi_ = f32_to_bf16_rne(v_);                        \
            float fh_ = __uint_as_float((unsigned)hi_ << 16);                \
            tshi[row_ * TS_LD + col_] = hi_;                                 \
            tslo[row_ * TS_LD + col_] = f32_to_bf16_rne(v_ - fh_);           \
        }                                                                    \
    }                                                                        \
} while (0)

__global__ __launch_bounds__(256, 2) void k_mlp(
        const unsigned short* __restrict__ h2hi, const unsigned short* __restrict__ h2lo,
        const unsigned short* __restrict__ w1hi, const unsigned short* __restrict__ w1lo,
        const float* __restrict__ b1,
        const unsigned short* __restrict__ w2hi, const unsigned short* __restrict__ w2lo,
        const float* __restrict__ b2,
        float* __restrict__ out) {
    __shared__ __align__(16) unsigned short tshi[MB * TS_LD];  // 16.5 KB
    __shared__ __align__(16) unsigned short tslo[MB * TS_LD];  // 16.5 KB
    int n0 = blockIdx.x * MB;
    int t  = threadIdx.x;
    int w  = t >> 6;
    int l  = t & 63;
    int lr = l & 15;     // A-row / B-col within tile
    int lg = l >> 4;     // k-group

    // ---- preload W1 fragments for this wave's 64 cols: 32 frags = 128 VGPR ----
    bf16x8 b1h[4][4], b1l[4][4];
    float  b1v[4];
    #pragma unroll
    for (int ct = 0; ct < 4; ct++) {
        int col = w * 64 + ct * 16 + lr;
        const unsigned short* bhp = w1hi + (size_t)col * IN_F + lg * 8;
        const unsigned short* blp = w1lo + (size_t)col * IN_F + lg * 8;
        #pragma unroll
        for (int kq = 0; kq < 4; kq++) {
            b1h[ct][kq] = *(const bf16x8*)(bhp + kq * 32);
            b1l[ct][kq] = *(const bf16x8*)(blp + kq * 32);
        }
        b1v[ct] = b1[col];
    }

    // ---- GEMM1 over 2 row-tiles, A double-buffered ----
    bf16x8 aAh[4], aAl[4], aBh[4], aBl[4];
    LOAD_A(aAh, aAl, 0);
    LOAD_A(aBh, aBl, 1);
    TILE(aAh, aAl, 0);
    TILE(aBh, aBl, 1);
    __syncthreads();

    // ---- GEMM2: waves 0-2, one 16-class col-tile each, W2 frags in regs ----
    if (w < 3) {
        int col = w * 16 + lr;                     // 0..47 (padded)
        bf16x8 b2h[8], b2l[8];
        const unsigned short* bhp = w2hi + (size_t)col * HID_F + lg * 8;
        const unsigned short* blp = w2lo + (size_t)col * HID_F + lg * 8;
        #pragma unroll
        for (int kk = 0; kk < 8; kk++) {
            b2h[kk] = *(const bf16x8*)(bhp + kk * 32);
            b2l[kk] = *(const bf16x8*)(blp + kk * 32);
        }
        float bias = (col < CLS_F) ? b2[col] : 0.f;
        #pragma unroll
        for (int rt2 = 0; rt2 < 2; rt2++) {
            const unsigned short* ahp = tshi + (rt2 * 16 + lr) * TS_LD + lg * 8;
            const unsigned short* alp = tslo + (rt2 * 16 + lr) * TS_LD + lg * 8;
            f32x4 acc0 = {0.f, 0.f, 0.f, 0.f};
            f32x4 acc1 = {0.f, 0.f, 0.f, 0.f};
            #pragma unroll
            for (int kk = 0; kk < 4; kk++) {
                bf16x8 a_h0 = *(const bf16x8*)(ahp + kk * 32);
                bf16x8 a_l0 = *(const bf16x8*)(alp + kk * 32);
                bf16x8 a_h1 = *(const bf16x8*)(ahp + (kk + 4) * 32);
                bf16x8 a_l1 = *(const bf16x8*)(alp + (kk + 4) * 32);
                acc0 = MFMA(a_h0, b2h[kk], acc0);
                acc1 = MFMA(a_h1, b2h[kk + 4], acc1);
                acc0 = MFMA(a_h0, b2l[kk], acc0);
                acc1 = MFMA(a_h1, b2l[kk + 4], acc1);
                acc0 = MFMA(a_l0, b2h[kk], acc0);
                acc1 = MFMA(a_l1, b2h[kk + 4], acc1);
            }
            if (col < CLS_F) {
                #pragma unroll
                for (int r = 0; r < 4; r++) {
                    int mrow = n0 + rt2 * 16 + lg * 4 + r;
                    out[(size_t)mrow * CLS_F + col] = acc0[r] + acc1[r] + bias;
                }
            }
        }
    }
}

// ---------------- launch ----------------

extern "C" void kernel_launch(void* const* d_in, const int* in_sizes, int n_in,
                              void* d_out, int out_size, void* d_ws, size_t ws_size,
                              hipStream_t stream) {
    const float* features = (const float*)d_in[0];
    const int*   src      = (const int*)d_in[1];
    const int*   dst      = (const int*)d_in[2];
    const float* W1       = (const float*)d_in[3];
    const float* b1       = (const float*)d_in[4];
    const float* W2       = (const float*)d_in[5];
    const float* b2       = (const float*)d_in[6];
    float*       out      = (float*)d_out;

    char* ws = (char*)d_ws;
    size_t off = 0;
    auto alloc = [&](size_t bytes) -> void* {
        void* p = ws + off;
        off += (bytes + 255) & ~(size_t)255;
        return p;
    };
    int*   counts = (int*)alloc((size_t)N_NODES * 4);
    int*   gcur   = (int*)alloc(256);
    int*   rowptr = (int*)alloc((size_t)N_NODES * 4);
    int*   cursor = (int*)alloc((size_t)N_NODES * 4);
    float* norm   = (float*)alloc((size_t)N_NODES * 4);
    float* norm2  = (float*)alloc((size_t)N_NODES * 4);
    unsigned short* csr = (unsigned short*)alloc((size_t)N_EDGES * 2);
    _Float16* xs  = (_Float16*)alloc((size_t)N_NODES * IN_F * 2);
    _Float16* h1  = (_Float16*)alloc((size_t)N_NODES * IN_F * 2);
    unsigned short* h2hi = (unsigned short*)alloc((size_t)N_NODES * IN_F * 2);
    unsigned short* h2lo = (unsigned short*)alloc((size_t)N_NODES * IN_F * 2);
    unsigned short* w1hi = (unsigned short*)alloc((size_t)HID_F * IN_F * 2);
    unsigned short* w1lo = (unsigned short*)alloc((size_t)HID_F * IN_F * 2);
    unsigned short* w2hi = (unsigned short*)alloc((size_t)CLS_P * HID_F * 2);
    unsigned short* w2lo = (unsigned short*)alloc((size_t)CLS_P * HID_F * 2);

    hipMemsetAsync(counts, 0, (size_t)N_NODES * 4, stream);

    int nb = (N_NODES + 255) / 256;   // 157
    k_count<<<(N_EDGES + 255) / 256, 256, 0, stream>>>(dst, counts, gcur);
    k_scanA<<<nb, 256, 0, stream>>>(counts, gcur, rowptr, cursor, norm, norm2);

    int prep_blocks = (IN_F * HID_F + CLS_P * HID_F + 255) / 256;   // 176
    k_fsp<<<5000 + prep_blocks, 256, 0, stream>>>(
        src, dst, cursor, csr, features, norm, xs, W1, W2, w1hi, w1lo, w2hi, w2lo);

    // hop1: h1 = fp16(norm2 * (A @ xs)); hop2: bf16 hi/lo split (trailing norm)
    k_hop<<<(N_NODES + 7) / 8, 256, 0, stream>>>(xs, h1, csr, rowptr, counts, norm2);
    k_hop_split<<<(N_NODES + 7) / 8, 256, 0, stream>>>(h1, h2hi, h2lo, csr, rowptr,
                                                       counts, norm);

    k_mlp<<<N_NODES / MB, 256, 0, stream>>>(h2hi, h2lo, w1hi, w1lo, b1, w2hi, w2lo, b2, out);
}

// Round 11
// 222.878 us; speedup vs baseline: 1.1776x; 1.0219x over previous
//
#include <hip/hip_runtime.h>

#define N_NODES 40000
#define N_EDGES 640000
#define IN_F 128
#define HID_F 256
#define CLS_F 40
#define CLS_P 48      // padded to 3 MFMA tiles of 16
#define MB 32         // nodes per block in fused MLP (2 row-tiles of 16; 1250 blocks)
#define TS_LD 264     // f16 row stride: MUST be >= 256 (row width); 528B, 16B-aligned
#define LO_SCALE 2048.0f          // W-lo pre-scale (keeps lo in f16 normal range)
#define LO_INV   4.8828125e-4f    // 1/2048

typedef __attribute__((ext_vector_type(8))) _Float16 f16x8;
typedef __attribute__((ext_vector_type(4))) float f32x4;
typedef __attribute__((ext_vector_type(4))) _Float16 half4;
typedef __attribute__((ext_vector_type(8))) _Float16 half8;

#define MFMA16(a, b, c) __builtin_amdgcn_mfma_f32_16x16x32_f16(a, b, c, 0, 0, 0)

// ---------------- CSR build ----------------

__global__ void k_count(const int* __restrict__ dst, int* __restrict__ counts,
                        int* __restrict__ gcur) {
    int e = blockIdx.x * blockDim.x + threadIdx.x;
    if (e == 0) *gcur = 0;              // consumed only by k_scanA (next launch)
    if (e < N_EDGES) atomicAdd(&counts[dst[e]], 1);
}

// single-kernel scan: local 256-scan + one atomicAdd to claim a disjoint range.
// rowptr ranges need NOT be monotonic across blocks -- any disjoint layout is a
// valid CSR (fill scatters via cursor, gathers read rowptr[gid] only).
__global__ void k_scanA(const int* __restrict__ counts, int* __restrict__ gcur,
                        int* __restrict__ rowptr, int* __restrict__ cursor,
                        float* __restrict__ norm, float* __restrict__ norm2) {
    __shared__ int s[256];
    __shared__ int base;
    int t = threadIdx.x;
    int i = blockIdx.x * 256 + t;
    int v = (i < N_NODES) ? counts[i] : 0;
    s[t] = v;
    __syncthreads();
    for (int off = 1; off < 256; off <<= 1) {
        int x = (t >= off) ? s[t - off] : 0;
        __syncthreads();
        s[t] += x;
        __syncthreads();
    }
    if (t == 255) base = atomicAdd(gcur, s[255]);
    __syncthreads();
    if (i < N_NODES) {
        int excl = base + s[t] - v;
        rowptr[i] = excl;
        cursor[i] = excl;
        float r = rsqrtf(fmaxf((float)v, 1.0f));
        norm[i] = r;
        norm2[i] = r * r;
    }
}

// ---------------- fill + scale + prep fused (all depend only on scanA) ----------------
// blocks [0,2500): csr fill; [2500,5000): xs = fp16(features*norm); [5000,5176): weight prep
// weight prep: whi = f16(W), wlo = f16((W - whi) * 2048), transposed [col][k]

__global__ __launch_bounds__(256) void k_fsp(
        const int* __restrict__ src, const int* __restrict__ dst,
        int* __restrict__ cursor, unsigned short* __restrict__ csr_src,
        const float* __restrict__ features, const float* __restrict__ norm,
        _Float16* __restrict__ xs,
        const float* __restrict__ W1, const float* __restrict__ W2,
        _Float16* __restrict__ w1hi, _Float16* __restrict__ w1lo,
        _Float16* __restrict__ w2hi, _Float16* __restrict__ w2lo) {
    int b = blockIdx.x;
    if (b < 2500) {
        int e = b * 256 + threadIdx.x;            // exactly N_EDGES threads
        int d = dst[e];
        int p = atomicAdd(&cursor[d], 1);
        csr_src[p] = (unsigned short)src[e];      // N_NODES < 65536
    } else if (b < 5000) {
        int i = (b - 2500) * 256 + threadIdx.x;   // 8 floats per thread, 640000 total
        float s = norm[i >> 4];                   // 16 threads per 128-elem row
        float4 a = ((const float4*)features)[i * 2];
        float4 c = ((const float4*)features)[i * 2 + 1];
        half8 h;
        h[0] = (_Float16)(a.x * s); h[1] = (_Float16)(a.y * s);
        h[2] = (_Float16)(a.z * s); h[3] = (_Float16)(a.w * s);
        h[4] = (_Float16)(c.x * s); h[5] = (_Float16)(c.y * s);
        h[6] = (_Float16)(c.z * s); h[7] = (_Float16)(c.w * s);
        ((half8*)xs)[i] = h;
    } else {
        int idx = (b - 5000) * 256 + threadIdx.x;
        if (idx < IN_F * HID_F) {
            int k = idx >> 8;
            int c = idx & 255;
            float v = W1[idx];
            _Float16 hi = (_Float16)v;
            w1hi[c * IN_F + k] = hi;
            w1lo[c * IN_F + k] = (_Float16)((v - (float)hi) * LO_SCALE);
        }
        int idx2 = idx - IN_F * HID_F;
        if (idx2 >= 0 && idx2 < CLS_P * HID_F) {
            int c = idx2 >> 8;
            int k = idx2 & 255;
            float v = (c < CLS_F) ? W2[k * CLS_F + c] : 0.f;
            _Float16 hi = (_Float16)v;
            w2hi[c * HID_F + k] = hi;
            w2lo[c * HID_F + k] = (_Float16)((v - (float)hi) * LO_SCALE);
        }
    }
}

// ---------------- propagation hop (gather, fp16 tables) ----------------
// 32 lanes per node, half4 (8B) per lane -> one 256B row read per edge.
// Pure gather-sum in fp32; dst-side scaling in epilogue; fp16 output.
// hop1: oscale = norm^2 ; hop2: oscale = norm (trailing SGConv norm).

__global__ __launch_bounds__(256) void k_hop(
        const _Float16* __restrict__ gin, _Float16* __restrict__ gout,
        const unsigned short* __restrict__ csr_src, const int* __restrict__ rowptr,
        const int* __restrict__ counts, const float* __restrict__ oscale) {
    int gid  = blockIdx.x * 8 + (threadIdx.x >> 5);
    int lane = threadIdx.x & 31;
    if (gid >= N_NODES) return;
    int start = rowptr[gid];
    int cnt   = counts[gid];
    const _Float16* base = gin + lane * 4;
    float4 acc = make_float4(0.f, 0.f, 0.f, 0.f);
    int i = 0;
    for (; i + 3 < cnt; i += 4) {
        int s0 = csr_src[start + i];     int s1 = csr_src[start + i + 1];
        int s2 = csr_src[start + i + 2]; int s3 = csr_src[start + i + 3];
        half4 v0 = *(const half4*)(base + (size_t)s0 * IN_F);
        half4 v1 = *(const half4*)(base + (size_t)s1 * IN_F);
        half4 v2 = *(const half4*)(base + (size_t)s2 * IN_F);
        half4 v3 = *(const half4*)(base + (size_t)s3 * IN_F);
        acc.x += (float)v0[0] + (float)v1[0] + (float)v2[0] + (float)v3[0];
        acc.y += (float)v0[1] + (float)v1[1] + (float)v2[1] + (float)v3[1];
        acc.z += (float)v0[2] + (float)v1[2] + (float)v2[2] + (float)v3[2];
        acc.w += (float)v0[3] + (float)v1[3] + (float)v2[3] + (float)v3[3];
    }
    for (; i < cnt; i++) {
        int s = csr_src[start + i];
        half4 v = *(const half4*)(base + (size_t)s * IN_F);
        acc.x += (float)v[0]; acc.y += (float)v[1];
        acc.z += (float)v[2]; acc.w += (float)v[3];
    }
    float sc = oscale[gid];
    half4 o;
    o[0] = (_Float16)(acc.x * sc); o[1] = (_Float16)(acc.y * sc);
    o[2] = (_Float16)(acc.z * sc); o[3] = (_Float16)(acc.w * sc);
    *(half4*)(gout + (size_t)gid * IN_F + lane * 4) = o;
}

// ---------------- fused MLP via f16 MFMA, split weights, weights-in-registers ----------------
// D = A*Whi + (A*Wlo')*2^-11, A exact in fp16 (h2 is fp16).  fp32 accum.
// Block: 4 waves, MB=32 rows (2 row-tiles of 16). Wave w owns GEMM1 cols
// [w*64, w*64+64): 32 W1 fragments (128 VGPR) preloaded ONCE. relu intermediate
// stored as single f16 plane in LDS (16.5 KB). GEMM2: waves 0-2, one 16-class
// col-tile each, 16 W2 fragments in registers.

__global__ __launch_bounds__(256, 2) void k_mlp(
        const _Float16* __restrict__ h2,
        const _Float16* __restrict__ w1hi, const _Float16* __restrict__ w1lo,
        const float* __restrict__ b1,
        const _Float16* __restrict__ w2hi, const _Float16* __restrict__ w2lo,
        const float* __restrict__ b2,
        float* __restrict__ out) {
    __shared__ __align__(16) _Float16 ts[MB * TS_LD];   // 16.5 KB
    int n0 = blockIdx.x * MB;
    int t  = threadIdx.x;
    int w  = t >> 6;
    int l  = t & 63;
    int lr = l & 15;     // A-row / B-col within tile
    int lg = l >> 4;     // k-group

    // ---- preload W1 fragments for this wave's 64 cols: 32 frags = 128 VGPR ----
    f16x8 b1h[4][4], b1l[4][4];
    float b1v[4];
    #pragma unroll
    for (int ct = 0; ct < 4; ct++) {
        int col = w * 64 + ct * 16 + lr;
        const _Float16* bhp = w1hi + (size_t)col * IN_F + lg * 8;
        const _Float16* blp = w1lo + (size_t)col * IN_F + lg * 8;
        #pragma unroll
        for (int kq = 0; kq < 4; kq++) {
            b1h[ct][kq] = *(const f16x8*)(bhp + kq * 32);
            b1l[ct][kq] = *(const f16x8*)(blp + kq * 32);
        }
        b1v[ct] = b1[col];
    }

    // ---- GEMM1 over 2 row-tiles; A loaded directly from fp16 h2 (no split) ----
    f16x8 aA[4], aB[4];
    {
        const _Float16* pa = h2 + (size_t)(n0 + lr) * IN_F + lg * 8;
        const _Float16* pb = h2 + (size_t)(n0 + 16 + lr) * IN_F + lg * 8;
        #pragma unroll
        for (int kq = 0; kq < 4; kq++) {
            aA[kq] = *(const f16x8*)(pa + kq * 32);
            aB[kq] = *(const f16x8*)(pb + kq * 32);
        }
    }
    #pragma unroll
    for (int rt = 0; rt < 2; rt++) {
        #pragma unroll
        for (int ct = 0; ct < 4; ct++) {
            f32x4 acch = {0.f, 0.f, 0.f, 0.f};
            f32x4 accl = {0.f, 0.f, 0.f, 0.f};
            #pragma unroll
            for (int kq = 0; kq < 4; kq++) {
                f16x8 a = rt == 0 ? aA[kq] : aB[kq];
                acch = MFMA16(a, b1h[ct][kq], acch);
                accl = MFMA16(a, b1l[ct][kq], accl);
            }
            int col = w * 64 + ct * 16 + lr;
            #pragma unroll
            for (int r = 0; r < 4; r++) {
                int row = rt * 16 + lg * 4 + r;     // C layout: row=(lane>>4)*4+reg
                float v = acch[r] + accl[r] * LO_INV + b1v[ct];
                ts[row * TS_LD + col] = (_Float16)(v > 0.f ? v : 0.f);
            }
        }
    }
    __syncthreads();

    // ---- GEMM2: waves 0-2, one 16-class col-tile each, W2 frags in regs ----
    if (w < 3) {
        int col = w * 16 + lr;                     // 0..47 (padded)
        f16x8 b2h[8], b2l[8];
        const _Float16* bhp = w2hi + (size_t)col * HID_F + lg * 8;
        const _Float16* blp = w2lo + (size_t)col * HID_F + lg * 8;
        #pragma unroll
        for (int kk = 0; kk < 8; kk++) {
            b2h[kk] = *(const f16x8*)(bhp + kk * 32);
            b2l[kk] = *(const f16x8*)(blp + kk * 32);
        }
        float bias = (col < CLS_F) ? b2[col] : 0.f;
        #pragma unroll
        for (int rt2 = 0; rt2 < 2; rt2++) {
            const _Float16* ahp = ts + (rt2 * 16 + lr) * TS_LD + lg * 8;
            f32x4 acch0 = {0.f, 0.f, 0.f, 0.f};
            f32x4 acch1 = {0.f, 0.f, 0.f, 0.f};
            f32x4 accl0 = {0.f, 0.f, 0.f, 0.f};
            f32x4 accl1 = {0.f, 0.f, 0.f, 0.f};
            #pragma unroll
            for (int kk = 0; kk < 4; kk++) {
                f16x8 a0 = *(const f16x8*)(ahp + kk * 32);
                f16x8 a1 = *(const f16x8*)(ahp + (kk + 4) * 32);
                acch0 = MFMA16(a0, b2h[kk], acch0);
                acch1 = MFMA16(a1, b2h[kk + 4], acch1);
                accl0 = MFMA16(a0, b2l[kk], accl0);
                accl1 = MFMA16(a1, b2l[kk + 4], accl1);
            }
            if (col < CLS_F) {
                #pragma unroll
                for (int r = 0; r < 4; r++) {
                    int mrow = n0 + rt2 * 16 + lg * 4 + r;
                    out[(size_t)mrow * CLS_F + col] =
                        (acch0[r] + acch1[r]) + (accl0[r] + accl1[r]) * LO_INV + bias;
                }
            }
        }
    }
}

// ---------------- launch ----------------

extern "C" void kernel_launch(void* const* d_in, const int* in_sizes, int n_in,
                              void* d_out, int out_size, void* d_ws, size_t ws_size,
                              hipStream_t stream) {
    const float* features = (const float*)d_in[0];
    const int*   src      = (const int*)d_in[1];
    const int*   dst      = (const int*)d_in[2];
    const float* W1       = (const float*)d_in[3];
    const float* b1       = (const float*)d_in[4];
    const float* W2       = (const float*)d_in[5];
    const float* b2       = (const float*)d_in[6];
    float*       out      = (float*)d_out;

    char* ws = (char*)d_ws;
    size_t off = 0;
    auto alloc = [&](size_t bytes) -> void* {
        void* p = ws + off;
        off += (bytes + 255) & ~(size_t)255;
        return p;
    };
    int*   counts = (int*)alloc((size_t)N_NODES * 4);
    int*   gcur   = (int*)alloc(256);
    int*   rowptr = (int*)alloc((size_t)N_NODES * 4);
    int*   cursor = (int*)alloc((size_t)N_NODES * 4);
    float* norm   = (float*)alloc((size_t)N_NODES * 4);
    float* norm2  = (float*)alloc((size_t)N_NODES * 4);
    unsigned short* csr = (unsigned short*)alloc((size_t)N_EDGES * 2);
    _Float16* xs  = (_Float16*)alloc((size_t)N_NODES * IN_F * 2);
    _Float16* h1  = (_Float16*)alloc((size_t)N_NODES * IN_F * 2);
    _Float16* h2  = (_Float16*)alloc((size_t)N_NODES * IN_F * 2);
    _Float16* w1hi = (_Float16*)alloc((size_t)HID_F * IN_F * 2);
    _Float16* w1lo = (_Float16*)alloc((size_t)HID_F * IN_F * 2);
    _Float16* w2hi = (_Float16*)alloc((size_t)CLS_P * HID_F * 2);
    _Float16* w2lo = (_Float16*)alloc((size_t)CLS_P * HID_F * 2);

    hipMemsetAsync(counts, 0, (size_t)N_NODES * 4, stream);

    int nb = (N_NODES + 255) / 256;   // 157
    k_count<<<(N_EDGES + 255) / 256, 256, 0, stream>>>(dst, counts, gcur);
    k_scanA<<<nb, 256, 0, stream>>>(counts, gcur, rowptr, cursor, norm, norm2);

    int prep_blocks = (IN_F * HID_F + CLS_P * HID_F + 255) / 256;   // 176
    k_fsp<<<5000 + prep_blocks, 256, 0, stream>>>(
        src, dst, cursor, csr, features, norm, xs, W1, W2, w1hi, w1lo, w2hi, w2lo);

    // hop1: h1 = fp16(norm2 * (A @ xs)); hop2: h2 = fp16(norm * (A @ h1))
    k_hop<<<(N_NODES + 7) / 8, 256, 0, stream>>>(xs, h1, csr, rowptr, counts, norm2);
    k_hop<<<(N_NODES + 7) / 8, 256, 0, stream>>>(h1, h2, csr, rowptr, counts, norm);

    k_mlp<<<N_NODES / MB, 256, 0, stream>>>(h2, w1hi, w1lo, b1, w2hi, w2lo, b2, out);
}